// Round 16
// baseline (95.453 us; speedup 1.0000x reference)
//
#include <hip/hip_runtime.h>
#include <hip/hip_bf16.h>
#include <cstddef>

#define NE 65536
#define ND 256
#define NP 8
#define SB 32                 // edges per ballot window
#define NSB (NE / SB)         // 2048 windows
#define TRS 16                // rows per main tile
#define NBLK2 256             // main blocks (1/CU)
#define MAXCH2 17             // max tiles per block chunk

typedef short bf16x8 __attribute__((ext_vector_type(8)));
typedef float f32x4  __attribute__((ext_vector_type(4)));
typedef const __attribute__((address_space(1))) unsigned int* gas_t;
typedef __attribute__((address_space(3))) unsigned int* las_t;

__device__ __forceinline__ unsigned short f2bf(float f) {
  unsigned int u = __float_as_uint(f);
  u += 0x7FFFu + ((u >> 16) & 1u);   // round-to-nearest-even
  return (unsigned short)(u >> 16);
}
__device__ __forceinline__ int load_idx(const void* idxraw, int is32, int e) {
  return is32 ? ((const int*)idxraw)[e] : (int)((const long long*)idxraw)[e];
}
// idx dtype sniff: odd 32-bit words all-zero <=> int64 (values < 8)
__device__ __forceinline__ int sniff_is32(const void* idxraw, int* lflag) {
  int tid = threadIdx.x;
  if (tid == 0) *lflag = 0;
  __syncthreads();
  const unsigned int* w = (const unsigned int*)idxraw;
  unsigned int val = w[(((int)blockIdx.x & 63) * 256 + (tid & 255)) * 2 + 1];
  if (__any(val != 0) && (tid & 63) == 0) atomicOr(lflag, 1);
  __syncthreads();
  return *lflag;
}

// ---- k_pre0: WbT frag (b<32), v (b<40), ballot histogram (b>=40) ----
__global__ __launch_bounds__(256) void k_pre0(const float* __restrict__ Wbil,
                                              const float* __restrict__ blr,
                                              const void* __restrict__ idxraw,
                                              unsigned short* __restrict__ WbT,
                                              float* __restrict__ v,
                                              int* __restrict__ counts) {
  int b = blockIdx.x, t = threadIdx.x;
  if (b < 32) {
    int s = b * 256 + t;
    int kt = s >> 10, c = (s >> 6) & 15, l = s & 63;
    int col = c * 16 + (l & 15);
    int k0 = kt * 32 + (l >> 4) * 8;
    union { uint4 u; unsigned short h[8]; } uu;
#pragma unroll
    for (int j = 0; j < 8; ++j)
      uu.h[j] = f2bf(Wbil[(k0 + j) * ND + col]);
    *(uint4*)(WbT + (size_t)s * 8) = uu.u;
  } else if (b < 40) {
    int p = b - 32;
    float s = 0.f;
    for (int k = 0; k < ND; ++k)
      s = fmaf(blr[p * ND + k], Wbil[k * ND + t], s);
    v[p * ND + t] = s;
  } else {
    __shared__ int lflag;
    int is32 = sniff_is32(idxraw, &lflag);
    int hb = b - 40;
    int w = t >> 6, l = t & 63;
    int e = hb * 256 + w * 64 + l;
    int p = load_idx(idxraw, is32, e);
    int sb0 = hb * 8 + w * 2;
#pragma unroll
    for (int q = 0; q < NP; ++q) {
      unsigned long long m = __ballot(p == q);
      if (l == q)      counts[q * NSB + sb0]     = __popcll(m & 0xFFFFFFFFull);
      if (l == 32 + q) counts[q * NSB + sb0 + 1] = __popcll(m >> 32);
    }
  }
}

// ---- k_scan: totals, CSR offsets, 16-row tile prefix, per-window bases ----
__global__ __launch_bounds__(256) void k_scan(const int* __restrict__ counts,
                                              int* __restrict__ hdr,
                                              int* __restrict__ bases) {
  __shared__ int part[NP][32], cpre[NP][32], cnt[NP], shoff[NP];
  int t = threadIdx.x;
  int q = t >> 5, i = t & 31;
  int s = 0;
  for (int j = 0; j < 64; ++j) s += counts[q * NSB + i * 64 + j];
  part[q][i] = s;
  __syncthreads();
  if (t < NP) {
    int run = 0;
    for (int k = 0; k < 32; ++k) { cpre[t][k] = run; run += part[t][k]; }
    cnt[t] = run;
  }
  __syncthreads();
  if (t == 0) {
    int o = 0, tt = 0;
    for (int p = 0; p < NP; ++p) {
      shoff[p] = o; hdr[p] = o; hdr[9 + p] = tt;
      o += cnt[p];
      tt += (cnt[p] + TRS - 1) / TRS;
    }
    hdr[NP] = o; hdr[9 + NP] = tt;
  }
  __syncthreads();
  int run = shoff[q] + cpre[q][i];
  for (int j = 0; j < 64; ++j) {
    int sb = i * 64 + j;
    bases[q * NSB + sb] = run;
    run += counts[q * NSB + sb];
  }
}

// ---- k_cpre: C_p = W_lr[p]^T @ W_bil (bf16 MFMA), B-frag layout ----
__global__ __launch_bounds__(256) void k_cpre(const float* __restrict__ Wlr,
                                              const unsigned short* __restrict__ WbT,
                                              unsigned short* __restrict__ Cst) {
  __shared__ unsigned short aF[2048 * 8];
  int blk = blockIdx.x;
  int p = blk >> 2;
  int i0 = (blk & 3) * 64;
  int tid = threadIdx.x;
  const float* Wp = Wlr + (size_t)p * ND * ND;
#pragma unroll
  for (int it = 0; it < 8; ++it) {
    int s = tid + it * 256;
    int kt = s >> 8, r = (s >> 6) & 3, l = s & 63;
    int i = r * 16 + (l & 15);
    int k0 = kt * 32 + (l >> 4) * 8;
    union { uint4 u; unsigned short h[8]; } uu;
#pragma unroll
    for (int j = 0; j < 8; ++j)
      uu.h[j] = f2bf(Wp[(size_t)(k0 + j) * ND + i0 + i]);
    *(uint4*)(aF + (size_t)s * 8) = uu.u;
  }
  __syncthreads();
  int w = tid >> 6, l = tid & 63;
  f32x4 zero = {0.f, 0.f, 0.f, 0.f};
  f32x4 acc[16];
#pragma unroll
  for (int c = 0; c < 16; ++c) acc[c] = zero;
  for (int kt = 0; kt < 8; ++kt) {
    bf16x8 a = *(const bf16x8*)(aF + (size_t)((kt * 4 + w) * 64 + l) * 8);
#pragma unroll
    for (int c = 0; c < 16; ++c) {
      bf16x8 bb = *(const bf16x8*)(WbT + (size_t)((kt * 16 + c) * 64 + l) * 8);
      acc[c] = __builtin_amdgcn_mfma_f32_16x16x32_bf16(a, bb, acc[c], 0, 0, 0);
    }
  }
  unsigned short* Cp = Cst + (size_t)p * ND * ND;
#pragma unroll
  for (int c = 0; c < 16; ++c) {
#pragma unroll
    for (int q = 0; q < 4; ++q) {
      int i = i0 + w * 16 + ((l >> 4) * 4) + q;
      int j = c * 16 + (l & 15);
      int pos = ((i >> 5) * 16 + (j >> 4)) * 512 + (((i >> 3) & 3) * 16 + (j & 15)) * 8 + (i & 7);
      Cp[pos] = f2bf(acc[c][q]);
    }
  }
}

// ---- k_perm: exact order-preserving CSR perm via ballot (no atomics) ----
__global__ __launch_bounds__(64) void k_perm(const void* __restrict__ idxraw,
                                             const int* __restrict__ bases,
                                             int* __restrict__ perm) {
  __shared__ int lflag;
  int l = threadIdx.x;
  int b = blockIdx.x;
  if (l == 0) lflag = 0;
  __syncthreads();
  {
    const unsigned int* w = (const unsigned int*)idxraw;
    unsigned int val = w[((b & 63) * 64 + l) * 2 + 1];
    if (__any(val != 0) && l == 0) atomicOr(&lflag, 1);
  }
  __syncthreads();
  int is32 = lflag;
  int base = b * SB;
  int p = (l < SB) ? load_idx(idxraw, is32, base + l) : 999;
  unsigned long long lt = (l == 63) ? (~0ull >> 1) : ((1ull << l) - 1ull);
  int rank = 0, gq = 0;
#pragma unroll
  for (int q = 0; q < NP; ++q) {
    unsigned long long m = __ballot(p == q);
    if (p == q) { rank = __popcll(m & lt); gq = q; }
  }
  if (l < SB) perm[bases[gq * NSB + b] + rank] = base + l;
}

// ---- k_main v16: ring-4 deep-pipelined persistent blocks. ----
// 256 blocks x 512 thr (1/CU); each owns ~17 contiguous 16-row CSR tiles.
// 4-slot LDS ring of fp32 (zs+zd) tiles staged via async global_load_lds;
// counted s_waitcnt vmcnt(12) keeps THREE tiles (12 loads/wave, 96 KB/CU)
// in flight through every compute phase — the queue never drains (the
// R3-R15 failure mode: drain -> ~50% memory duty -> ~2 TB/s). No global
// stores inside the loop (stores share the vmcnt counter and would corrupt
// the counted waits): outputs buffer in LDS, flushed once at the end.
__global__ __launch_bounds__(512, 2) void k_main(const float* __restrict__ zsrc,
                                                 const float* __restrict__ zdst,
                                                 const int* __restrict__ perm,
                                                 const int* __restrict__ hdr,
                                                 const unsigned short* __restrict__ Cst,
                                                 const float* __restrict__ v,
                                                 const float* __restrict__ bbil,
                                                 float* __restrict__ out) {
  __shared__ float slab[4][32][256];       // 128 KiB: [slot][0-15 zs | 16-31 zd][1KB row]
  __shared__ float red[8][TRS];            // 512 B
  __shared__ float outv[MAXCH2 * TRS];     // 1.06 KiB
  __shared__ int eidsAll[MAXCH2 * TRS];    // 1.06 KiB
  __shared__ int pExp[MAXCH2], pNrow[MAXCH2];
  __shared__ int shdr[18];
  int tid = threadIdx.x;
  if (tid < 18) shdr[tid] = hdr[tid];
  __syncthreads();
  int ntiles = shdr[17];
  int chunk = (ntiles + NBLK2 - 1) / NBLK2;        // <= MAXCH2
  int t0 = (int)blockIdx.x * chunk;
  if (t0 >= ntiles) return;
  int nt = ntiles - t0; if (nt > chunk) nt = chunk;
  float bb0 = bbil[0];
  // preamble: decode chunk tiles, preload eids
  for (int j = tid; j < nt * TRS; j += 512) {
    int tl = j >> 4, tt = t0 + tl;
    int p = 0;
    while (p < NP - 1 && tt >= shdr[9 + p + 1]) ++p;
    int ebase = shdr[p] + (tt - shdr[9 + p]) * TRS;
    int cend = shdr[p + 1];
    int r = j & 15;
    int re = ebase + r; if (re > cend - 1) re = cend - 1;
    eidsAll[j] = perm[re];
    if (r == 0) {
      pExp[tl] = p;
      int nr = cend - ebase; pNrow[tl] = nr > TRS ? TRS : nr;
    }
  }
  __syncthreads();   // drains all preamble loads; vmcnt = 0 for every wave

  int w = tid >> 6, l = tid & 63;
  int hi = l >> 4, rr = l & 15;
  unsigned sxr = (unsigned)(rr & 7);

  // per wave: 4 async loads per tile (zs rows {2w,2w+1}, zd rows {2w,2w+1})
#define STAGE(TL, SL)                                                            \
  {                                                                              \
    int _tl = (TL), _sl = (SL);                                                  \
    _Pragma("unroll")                                                            \
    for (int _i = 0; _i < 2; ++_i) {                                             \
      int _r = w * 2 + _i;                                                       \
      int _e = eidsAll[_tl * TRS + _r];                                          \
      unsigned _off = (((unsigned)l ^ (unsigned)(_r & 7)) << 2);                 \
      __builtin_amdgcn_global_load_lds((gas_t)(const void*)(zsrc + (size_t)_e * ND + _off), \
          (las_t)(void*)&slab[_sl][_r][0], 16, 0, 0);                            \
      __builtin_amdgcn_global_load_lds((gas_t)(const void*)(zdst + (size_t)_e * ND + _off), \
          (las_t)(void*)&slab[_sl][16 + _r][0], 16, 0, 0);                       \
    }                                                                            \
  }

  // prologue: fill the ring
#pragma unroll
  for (int k = 0; k < 4; ++k)
    if (k < nt) STAGE(k, k);

  int curP = -1;
  bf16x8 bfr[2][8];
  float vloc[2];
  f32x4 zero = {0.f, 0.f, 0.f, 0.f};

  for (int tl = 0; tl < nt; ++tl) {
    int sl = tl & 3;
    int left = nt - 1 - tl; if (left > 3) left = 3;
    switch (left) {        // wait: this tile's 4 loads done; 'left' tiles stay in flight
      case 3: asm volatile("s_waitcnt vmcnt(12)" ::: "memory"); break;
      case 2: asm volatile("s_waitcnt vmcnt(8)"  ::: "memory"); break;
      case 1: asm volatile("s_waitcnt vmcnt(4)"  ::: "memory"); break;
      default: asm volatile("s_waitcnt vmcnt(0)" ::: "memory"); break;
    }
    __builtin_amdgcn_sched_barrier(0);
    __builtin_amdgcn_s_barrier();

    int p = pExp[tl];
    if (p != curP) {
      curP = p;
      const unsigned short* Cp = Cst + (size_t)p * ND * ND;
#pragma unroll
      for (int cl = 0; cl < 2; ++cl) {
#pragma unroll
        for (int kt = 0; kt < 8; ++kt)
          bfr[cl][kt] = *(const bf16x8*)(Cp + (size_t)((kt * 16 + (w * 2 + cl)) * 64 + l) * 8);
        vloc[cl] = v[p * ND + (w * 2 + cl) * 16 + rr];
      }
    }

    // GEMM: one 16-row strip; wave w covers col-tiles {2w, 2w+1}
    const char* zsb = (const char*)&slab[sl][0][0];
    const char* rowb = zsb + rr * 1024;
    f32x4 acc0 = zero, acc1 = zero;
#pragma unroll
    for (int kt = 0; kt < 8; ++kt) {
      unsigned g0 = (unsigned)(kt * 8 + hi * 2);
      float4 f0 = *(const float4*)(rowb + ((g0 ^ sxr) << 4));
      float4 f1 = *(const float4*)(rowb + (((g0 + 1) ^ sxr) << 4));
      union { bf16x8 vv; unsigned short h[8]; } ua;
      ua.h[0] = f2bf(f0.x); ua.h[1] = f2bf(f0.y); ua.h[2] = f2bf(f0.z); ua.h[3] = f2bf(f0.w);
      ua.h[4] = f2bf(f1.x); ua.h[5] = f2bf(f1.y); ua.h[6] = f2bf(f1.z); ua.h[7] = f2bf(f1.w);
      acc0 = __builtin_amdgcn_mfma_f32_16x16x32_bf16(ua.vv, bfr[0][kt], acc0, 0, 0, 0);
      acc1 = __builtin_amdgcn_mfma_f32_16x16x32_bf16(ua.vv, bfr[1][kt], acc1, 0, 0, 0);
    }
    // fused epilogue: fp32 z_dst from slab rows 16..31
#pragma unroll
    for (int q = 0; q < 4; ++q) {
      int row = hi * 4 + q;                  // D-layout: col=l&15, row=(l>>4)*4+reg
      const char* zdb = zsb + (16 + row) * 1024;
      unsigned sw = (unsigned)(row & 7);
      int col0 = (w * 2 + 0) * 16 + rr;
      int col1 = col0 + 16;
      float z0 = *(const float*)(zdb + ((((unsigned)(col0 >> 2) ^ sw) << 4) | ((unsigned)(col0 & 3) << 2)));
      float z1 = *(const float*)(zdb + ((((unsigned)(col1 >> 2) ^ sw) << 4) | ((unsigned)(col1 & 3) << 2)));
      float sv = fmaf(acc0[q] + vloc[0], z0, 0.f);
      sv = fmaf(acc1[q] + vloc[1], z1, sv);
      sv += __shfl_xor(sv, 1, 64);
      sv += __shfl_xor(sv, 2, 64);
      sv += __shfl_xor(sv, 4, 64);
      sv += __shfl_xor(sv, 8, 64);
      if (rr == 0) red[w][row] = sv;
    }
    asm volatile("s_waitcnt lgkmcnt(0)" ::: "memory");
    __builtin_amdgcn_sched_barrier(0);
    __builtin_amdgcn_s_barrier();            // red ready; all waves done with slab[sl]

    if (tid < TRS) {
      float sc = 0.f;
#pragma unroll
      for (int ww = 0; ww < 8; ++ww) sc += red[ww][tid];
      outv[tl * TRS + tid] = sc;             // LDS only — no vmcnt traffic
    }
    if (tl + 4 < nt) STAGE(tl + 4, sl);      // refill freed slot
  }
#undef STAGE

  __syncthreads();
  for (int j = tid; j < nt * TRS; j += 512) {
    int tl = j >> 4, r = j & 15;
    if (r < pNrow[tl]) out[eidsAll[j]] = outv[j] + bb0;
  }
}

extern "C" void kernel_launch(void* const* d_in, const int* in_sizes, int n_in,
                              void* d_out, int out_size, void* d_ws, size_t ws_size,
                              hipStream_t stream) {
  // setup_inputs() dict order: z_src, z_dst, W_lr, b_lr, W_bil, b_bil, lr_pair_idx
  const float* zsrc = (const float*)d_in[0];
  const float* zdst = (const float*)d_in[1];
  const float* Wlr  = (const float*)d_in[2];
  const float* blr  = (const float*)d_in[3];
  const float* Wbil = (const float*)d_in[4];
  const float* bbil = (const float*)d_in[5];
  const void*  idx  = (const void*)d_in[6];
  float* out = (float*)d_out;

  char* ws = (char*)d_ws;
  int* hdr    = (int*)ws;                                  // 72 B
  int* counts = (int*)(ws + 4096);                         // 64 KiB [q][sb]
  int* bases  = (int*)(ws + 73728);                        // 64 KiB [q][sb]
  unsigned short* WbT = (unsigned short*)(ws + 139264);    // 128 KiB
  float* v            = (float*)(ws + 270336);             // 8 KiB
  unsigned short* Cst = (unsigned short*)(ws + 278528);    // 1 MiB
  int* perm           = (int*)(ws + 1327104);              // 256 KiB

  k_pre0<<<296, 256, 0, stream>>>(Wbil, blr, idx, WbT, v, counts);
  k_scan<<<1, 256, 0, stream>>>(counts, hdr, bases);
  k_cpre<<<32, 256, 0, stream>>>(Wlr, WbT, Cst);
  k_perm<<<NSB, 64, 0, stream>>>(idx, bases, perm);
  k_main<<<NBLK2, 512, 0, stream>>>(zsrc, zdst, perm, hdr, Cst, v, bbil, out);
}

// Round 17
// 75.882 us; speedup vs baseline: 1.2579x; 1.2579x over previous
//
#include <hip/hip_runtime.h>
#include <hip/hip_bf16.h>
#include <cstddef>

#define NE 65536
#define ND 256
#define NP 8
#define RBLK 64              // hist/scatter blocks
#define EPB (NE / RBLK)      // 1024 edges per routing block
#define TR 32                // rows per main tile
#define MAXT 2056            // max tiles: 2048 + 8

typedef short bf16x8 __attribute__((ext_vector_type(8)));
typedef float f32x4  __attribute__((ext_vector_type(4)));

__device__ __forceinline__ unsigned short f2bf(float f) {
  unsigned int u = __float_as_uint(f);
  u += 0x7FFFu + ((u >> 16) & 1u);   // round-to-nearest-even
  return (unsigned short)(u >> 16);
}
__device__ __forceinline__ float bf2f(unsigned short h) {
  return __uint_as_float(((unsigned int)h) << 16);
}
__device__ __forceinline__ int load_idx(const void* idxraw, int is32, int e) {
  return is32 ? ((const int*)idxraw)[e] : (int)((const long long*)idxraw)[e];
}
// idx dtype sniff: odd 32-bit words all-zero <=> int64 (values < 8)
__device__ __forceinline__ int sniff_is32(const void* idxraw, int* lflag, int bsel) {
  int tid = threadIdx.x;
  if (tid == 0) *lflag = 0;
  __syncthreads();
  const unsigned int* w = (const unsigned int*)idxraw;
  unsigned int val = w[((bsel & 63) * 256 + tid) * 2 + 1];
  if (__any(val != 0) && (tid & 63) == 0) atomicOr(lflag, 1);
  __syncthreads();
  return *lflag;
}

// ---- fused prep (W_bil frag + v) and per-block histogram (R12 verbatim) ----
__global__ __launch_bounds__(256) void k_pre0(const float* __restrict__ Wbil,
                                              const float* __restrict__ blr,
                                              const void* __restrict__ idxraw,
                                              unsigned short* __restrict__ WbT,
                                              float* __restrict__ v,
                                              int* __restrict__ counts) {
  int b = blockIdx.x, t = threadIdx.x;
  if (b < 32) {
    int s = b * 256 + t;
    int kt = s >> 10, c = (s >> 6) & 15, l = s & 63;
    int col = c * 16 + (l & 15);
    int k0 = kt * 32 + (l >> 4) * 8;
    union { uint4 u; unsigned short h[8]; } uu;
#pragma unroll
    for (int j = 0; j < 8; ++j)
      uu.h[j] = f2bf(Wbil[(k0 + j) * ND + col]);
    *(uint4*)(WbT + (size_t)s * 8) = uu.u;
  } else if (b < 40) {
    int p = b - 32;
    float s = 0.f;
    for (int k = 0; k < ND; ++k)
      s = fmaf(blr[p * ND + k], Wbil[k * ND + t], s);
    v[p * ND + t] = s;
  } else {
    __shared__ int h[NP];
    __shared__ int lflag;
    int hb = b - 40;
    int is32 = sniff_is32(idxraw, &lflag, hb);
    if (t < NP) h[t] = 0;
    __syncthreads();
    int base = hb * EPB;
#pragma unroll
    for (int i = 0; i < EPB / 256; ++i) {
      int p = load_idx(idxraw, is32, base + t + i * 256);
      atomicAdd(&h[p], 1);
    }
    __syncthreads();
    if (t < NP) counts[hb * NP + t] = h[t];
  }
}

// ---- scan: totals, CSR offsets, 32-row tile prefix, per-block bases ----
__global__ __launch_bounds__(64) void k_scan(const int* __restrict__ counts,
                                             int* __restrict__ hdr,
                                             int* __restrict__ bases) {
  __shared__ int cnt[NP];
  __shared__ int off[NP + 1];
  int q = threadIdx.x;
  if (q < NP) {
    int s = 0;
    for (int b = 0; b < RBLK; ++b) s += counts[b * NP + q];
    cnt[q] = s;
  }
  __syncthreads();
  if (q == 0) {
    int o = 0, tt = 0;
    for (int p = 0; p < NP; ++p) {
      off[p] = o; hdr[p] = o; hdr[9 + p] = tt;
      o += cnt[p];
      tt += (cnt[p] + TR - 1) / TR;
    }
    off[NP] = o; hdr[NP] = o; hdr[9 + NP] = tt;
  }
  __syncthreads();
  if (q < NP) {
    int run = off[q];
    for (int b = 0; b < RBLK; ++b) {
      bases[b * NP + q] = run;
      run += counts[b * NP + q];
    }
  }
}

// ---- fused CSR scatter + C_p precompute (R12 verbatim) ----
__global__ __launch_bounds__(256) void k_sc2(const void* __restrict__ idxraw,
                                             const int* __restrict__ bases,
                                             int* __restrict__ perm,
                                             const float* __restrict__ Wlr,
                                             const unsigned short* __restrict__ WbT,
                                             unsigned short* __restrict__ Cst) {
  __shared__ unsigned short aF[2048 * 8];   // used by cpre half only
  int b = blockIdx.x, tid = threadIdx.x;
  if (b < 64) {
    __shared__ int cur[NP];
    __shared__ int lflag;
    int is32 = sniff_is32(idxraw, &lflag, b);
    if (tid < NP) cur[tid] = bases[b * NP + tid];
    __syncthreads();
    int base = b * EPB;
#pragma unroll
    for (int i = 0; i < EPB / 256; ++i) {
      int e = base + tid + i * 256;
      int p = load_idx(idxraw, is32, e);
      int slot = atomicAdd(&cur[p], 1);
      perm[slot] = e;
    }
    return;
  }
  int blk = b - 64;
  int p = blk >> 2;
  int i0 = (blk & 3) * 64;
  const float* Wp = Wlr + (size_t)p * ND * ND;
#pragma unroll
  for (int it = 0; it < 8; ++it) {
    int s = tid + it * 256;
    int kt = s >> 8, r = (s >> 6) & 3, l = s & 63;
    int i = r * 16 + (l & 15);
    int k0 = kt * 32 + (l >> 4) * 8;
    union { uint4 u; unsigned short h[8]; } uu;
#pragma unroll
    for (int j = 0; j < 8; ++j)
      uu.h[j] = f2bf(Wp[(size_t)(k0 + j) * ND + i0 + i]);
    *(uint4*)(aF + (size_t)s * 8) = uu.u;
  }
  __syncthreads();
  int w = tid >> 6, l = tid & 63;
  f32x4 zero = {0.f, 0.f, 0.f, 0.f};
  f32x4 acc[16];
#pragma unroll
  for (int c = 0; c < 16; ++c) acc[c] = zero;
  for (int kt = 0; kt < 8; ++kt) {
    bf16x8 a = *(const bf16x8*)(aF + (size_t)((kt * 4 + w) * 64 + l) * 8);
#pragma unroll
    for (int c = 0; c < 16; ++c) {
      bf16x8 bb = *(const bf16x8*)(WbT + (size_t)((kt * 16 + c) * 64 + l) * 8);
      acc[c] = __builtin_amdgcn_mfma_f32_16x16x32_bf16(a, bb, acc[c], 0, 0, 0);
    }
  }
  unsigned short* Cp = Cst + (size_t)p * ND * ND;
#pragma unroll
  for (int c = 0; c < 16; ++c) {
#pragma unroll
    for (int q = 0; q < 4; ++q) {
      int i = i0 + w * 16 + ((l >> 4) * 4) + q;
      int j = c * 16 + (l & 15);
      int pos = ((i >> 5) * 16 + (j >> 4)) * 512 + (((i >> 3) & 3) * 16 + (j & 15)) * 8 + (i & 7);
      Cp[pos] = f2bf(acc[c][q]);
    }
  }
}

// ---- main v17: R12 body + staging ILP. ----
// Changes vs R12 (the 63-67us best): (a) launch_bounds(512,6) -> VGPR cap 85
// (R12's cap of 64 yielded VGPR=28: only ~2 of 8 staging loads in flight per
// thread -> latency-serialized staging was the suspected wall); (b) all 8
// float4 loads issued back-to-back into registers BEFORE any cvt/ds_write
// (per-CU bytes-in-flight 48KB -> ~192KB); (c) per-wave eids via wave-uniform
// scalar loads of perm (no eids-LDS round-trip, no pre-staging barrier);
// (d) per-thread hdr decode (no shdr barrier). GEMM/epilogue identical.
__global__ __launch_bounds__(512, 6) void k_main(const float* __restrict__ zsrc,
                                                 const float* __restrict__ zdst,
                                                 const int* __restrict__ perm,
                                                 const int* __restrict__ hdr,
                                                 const unsigned short* __restrict__ Cst,
                                                 const float* __restrict__ v,
                                                 const float* __restrict__ bbil,
                                                 float* __restrict__ out) {
  __shared__ unsigned short zs[8192];    // 16 KiB: A-frag layout, granule-XOR
  __shared__ unsigned short zd[8192];    // 16 KiB: row-major 512B/row, XOR
  __shared__ float red[8][TR];           // 1 KiB
  int tid = threadIdx.x;
  int bid = blockIdx.x;
  if (bid >= hdr[9 + NP]) return;
  // expert decode: p = #{q in 1..7 : tile_prefix[q] <= bid}
  int p = 0;
#pragma unroll
  for (int q = 1; q < NP; ++q) p += (bid >= hdr[9 + q]) ? 1 : 0;
  int t = bid - hdr[9 + p];
  int cbeg = hdr[p], cend = hdr[p + 1];
  int ebase = cbeg + t * TR;
  int nrow = cend - ebase; if (nrow > TR) nrow = TR;
  int w = tid >> 6, l = tid & 63;

  // ---- wave-uniform eids for this wave's 4 rows (scalar loads, no LDS) ----
  int e4[4];
#pragma unroll
  for (int i = 0; i < 4; ++i) {
    int r = ebase + w * 4 + i; if (r > cend - 1) r = cend - 1;
    e4[i] = perm[r];
  }
  // ---- batched staging loads: all 8 in flight before any cvt/write ----
  float4 fs[4], fd[4];
#pragma unroll
  for (int i = 0; i < 4; ++i)
    fs[i] = *(const float4*)(zsrc + (size_t)e4[i] * ND + l * 4);
#pragma unroll
  for (int i = 0; i < 4; ++i)
    fd[i] = *(const float4*)(zdst + (size_t)e4[i] * ND + l * 4);
  // ---- cvt + swizzled LDS writes (R12 layout verbatim) ----
  int kt0 = l >> 3, q0 = (l >> 1) & 3, par0 = l & 1;
#pragma unroll
  for (int i = 0; i < 4; ++i) {
    int row = w * 4 + i;
    union { unsigned long long u; unsigned short h[4]; } us, ud;
    us.h[0] = f2bf(fs[i].x); us.h[1] = f2bf(fs[i].y);
    us.h[2] = f2bf(fs[i].z); us.h[3] = f2bf(fs[i].w);
    ud.h[0] = f2bf(fd[i].x); ud.h[1] = f2bf(fd[i].y);
    ud.h[2] = f2bf(fd[i].z); ud.h[3] = f2bf(fd[i].w);
    unsigned g = (unsigned)((kt0 * 2 + (row >> 4)) * 64 + (row & 15) + 16 * q0);
    g ^= ((g >> 6) & 7u) << 1;
    *(unsigned long long*)((char*)zs + g * 16 + par0 * 8) = us.u;
    *(unsigned long long*)((char*)zd + ((unsigned)(row * 512 + l * 8) ^ (((unsigned)row & 7u) << 5))) = ud.u;
  }
  __syncthreads();

  // ---- GEMM: wave w covers col-tiles {2w, 2w+1}; 2 row-strips; B from L2 ----
  const unsigned short* Cp = Cst + (size_t)p * ND * ND;
  f32x4 zero = {0.f, 0.f, 0.f, 0.f};
  f32x4 acc[2][2];
#pragma unroll
  for (int sr = 0; sr < 2; ++sr)
#pragma unroll
    for (int cl = 0; cl < 2; ++cl) acc[sr][cl] = zero;
  int hh = l >> 4, rr = l & 15;
#pragma unroll
  for (int kt = 0; kt < 8; ++kt) {
    bf16x8 a[2];
#pragma unroll
    for (int sr = 0; sr < 2; ++sr) {
      unsigned g = (unsigned)((kt * 2 + sr) * 64 + l);
      g ^= ((g >> 6) & 7u) << 1;
      a[sr] = *(const bf16x8*)((const char*)zs + g * 16);
    }
#pragma unroll
    for (int cl = 0; cl < 2; ++cl) {
      bf16x8 bb = *(const bf16x8*)(Cp + (size_t)((kt * 16 + (w * 2 + cl)) * 64 + l) * 8);
#pragma unroll
      for (int sr = 0; sr < 2; ++sr)
        acc[sr][cl] = __builtin_amdgcn_mfma_f32_16x16x32_bf16(a[sr], bb, acc[sr][cl], 0, 0, 0);
    }
  }

  // ---- fused epilogue: bf16 z_dst from LDS; 4-lane-group reduce ----
  float vloc[2];
#pragma unroll
  for (int cl = 0; cl < 2; ++cl)
    vloc[cl] = v[p * ND + (w * 2 + cl) * 16 + rr];
#pragma unroll
  for (int sr = 0; sr < 2; ++sr) {
#pragma unroll
    for (int q = 0; q < 4; ++q) {
      int row = sr * 16 + hh * 4 + q;          // D-layout: col=l&15, row=(l>>4)*4+reg
      unsigned swz = ((unsigned)row & 7u) << 5;
      float sv = 0.f;
#pragma unroll
      for (int cl = 0; cl < 2; ++cl) {
        int col = (w * 2 + cl) * 16 + rr;
        unsigned byte = ((unsigned)(row * 512 + col * 2)) ^ swz;
        sv = fmaf(acc[sr][cl][q] + vloc[cl], bf2f(*(const unsigned short*)((const char*)zd + byte)), sv);
      }
      sv += __shfl_xor(sv, 1, 64);
      sv += __shfl_xor(sv, 2, 64);
      sv += __shfl_xor(sv, 4, 64);
      sv += __shfl_xor(sv, 8, 64);
      if (rr == 0) red[w][row] = sv;
    }
  }
  __syncthreads();
  if (tid < TR && tid < nrow) {
    float sc = bbil[0];
#pragma unroll
    for (int ww = 0; ww < 8; ++ww) sc += red[ww][tid];
    out[perm[ebase + tid]] = sc;
  }
}

extern "C" void kernel_launch(void* const* d_in, const int* in_sizes, int n_in,
                              void* d_out, int out_size, void* d_ws, size_t ws_size,
                              hipStream_t stream) {
  // setup_inputs() dict order: z_src, z_dst, W_lr, b_lr, W_bil, b_bil, lr_pair_idx
  const float* zsrc = (const float*)d_in[0];
  const float* zdst = (const float*)d_in[1];
  const float* Wlr  = (const float*)d_in[2];
  const float* blr  = (const float*)d_in[3];
  const float* Wbil = (const float*)d_in[4];
  const float* bbil = (const float*)d_in[5];
  const void*  idx  = (const void*)d_in[6];
  float* out = (float*)d_out;

  char* ws = (char*)d_ws;
  int* hdr    = (int*)ws;                                  // 72 B
  int* counts = (int*)(ws + 4096);                         // 2 KiB
  int* bases  = (int*)(ws + 8192);                         // 2 KiB
  int* perm   = (int*)(ws + 16384);                        // 256 KiB (CSR)
  unsigned short* WbT = (unsigned short*)(ws + 16384 + (size_t)NE * 4);            // 128 KiB
  float* v = (float*)(ws + 16384 + (size_t)NE * 4 + 131072);                       // 8 KiB
  unsigned short* Cst = (unsigned short*)(ws + 16384 + (size_t)NE * 4 + 131072 + 8192); // 1 MiB

  k_pre0<<<104, 256, 0, stream>>>(Wbil, blr, idx, WbT, v, counts);
  k_scan<<<1, 64, 0, stream>>>(counts, hdr, bases);
  k_sc2<<<96, 256, 0, stream>>>(idx, bases, perm, Wlr, WbT, Cst);
  k_main<<<MAXT, 512, 0, stream>>>(zsrc, zdst, perm, hdr, Cst, v, bbil, out);
}